// Round 1
// baseline (445.455 us; speedup 1.0000x reference)
//
#include <hip/hip_runtime.h>
#include <hip/hip_bf16.h>

// Problem constants (T,B,I,H,O) = (2048,16,256,256,8)
#define TT     2048
#define BBATCH 16
#define IDIM   256
#define HDIM   256
#define ODIM   8
#define MM (TT * BBATCH)   // 32768 rows (t*B + b)
#define NN (HDIM * ODIM)   // 2048 cols (h*8 + o)
#define KK IDIM            // 256

typedef __attribute__((ext_vector_type(8))) short bf16x8;
typedef __attribute__((ext_vector_type(4))) float f32x4;

__device__ __forceinline__ unsigned short f2bfu(float f) {
  __hip_bfloat16 h = __float2bfloat16(f);
  return *reinterpret_cast<unsigned short*>(&h);
}

// ---- prep: x (f32 [M][K]) -> bf16 [M][K] ----
__global__ __launch_bounds__(256) void conv_x_kernel(const float* __restrict__ x,
                                                     unsigned short* __restrict__ xb) {
  size_t id = (size_t)blockIdx.x * 256 + threadIdx.x;  // 4 elements each
  float4 v = reinterpret_cast<const float4*>(x)[id];
  ushort4 o;
  o.x = f2bfu(v.x); o.y = f2bfu(v.y); o.z = f2bfu(v.z); o.w = f2bfu(v.w);
  reinterpret_cast<ushort4*>(xb)[id] = o;
}

// ---- prep: B_w (f32 [O][H][I]) -> bf16 W[n=h*8+o][k], bias_n[n] = B_b[o][h] ----
__global__ __launch_bounds__(64) void conv_w_kernel(const float* __restrict__ Bw,
                                                    const float* __restrict__ Bb,
                                                    unsigned short* __restrict__ wb,
                                                    float* __restrict__ biasn) {
  int n = blockIdx.x;        // 0..2047
  int j = threadIdx.x;       // 0..63 (4 k-elements each)
  int o = n & 7, h = n >> 3;
  const float* src = Bw + ((size_t)o * HDIM + h) * IDIM;
  float4 v = reinterpret_cast<const float4*>(src)[j];
  ushort4 p;
  p.x = f2bfu(v.x); p.y = f2bfu(v.y); p.z = f2bfu(v.z); p.w = f2bfu(v.w);
  reinterpret_cast<ushort4*>(wb + (size_t)n * KK)[j] = p;
  if (j == 0) biasn[n] = Bb[o * HDIM + h];
}

// ---- main GEMM + fused epilogue ----
// C[m][n] = sum_k X[m][k] * W[n][k] + bias[n]
// if alpha==1: act = tanh(C + sigma[n]*noise[m][n]) ; else: act = C (pre-activation, scan fixes it)
template <bool PREP>
__global__ __launch_bounds__(256) void gemm_kernel(
    const unsigned short* __restrict__ xb, const unsigned short* __restrict__ wb,
    const float* __restrict__ biasn,
    const float* __restrict__ xf, const float* __restrict__ Bw, const float* __restrict__ Bb,
    const float* __restrict__ noise, const float* __restrict__ sigma,
    const float* __restrict__ alphap,
    float* __restrict__ act) {
  const int tid = threadIdx.x;
  const int l = tid & 63;
  const int w = tid >> 6;              // 4 waves, 2x2
  const int wr = w >> 1, wc = w & 1;
  const int m0 = blockIdx.y * 128 + wr * 64;
  const int n0 = blockIdx.x * 128 + wc * 64;
  const int lr = l & 15, lg = l >> 4;

  f32x4 acc[4][4];
#pragma unroll
  for (int mi = 0; mi < 4; ++mi)
#pragma unroll
    for (int ni = 0; ni < 4; ++ni) acc[mi][ni] = (f32x4){0.f, 0.f, 0.f, 0.f};

  for (int kt = 0; kt < KK / 32; ++kt) {
    const int kk = kt * 32 + lg * 8;   // this lane-group's 8-element k-chunk
    bf16x8 a[4], b[4];
    if constexpr (PREP) {
#pragma unroll
      for (int mi = 0; mi < 4; ++mi)
        a[mi] = *reinterpret_cast<const bf16x8*>(xb + (size_t)(m0 + mi * 16 + lr) * KK + kk);
#pragma unroll
      for (int ni = 0; ni < 4; ++ni)
        b[ni] = *reinterpret_cast<const bf16x8*>(wb + (size_t)(n0 + ni * 16 + lr) * KK + kk);
    } else {
#pragma unroll
      for (int mi = 0; mi < 4; ++mi) {
        const float* ap = xf + (size_t)(m0 + mi * 16 + lr) * KK + kk;
        float4 u0 = *reinterpret_cast<const float4*>(ap);
        float4 u1 = *reinterpret_cast<const float4*>(ap + 4);
        bf16x8 t;
        t[0] = (short)f2bfu(u0.x); t[1] = (short)f2bfu(u0.y);
        t[2] = (short)f2bfu(u0.z); t[3] = (short)f2bfu(u0.w);
        t[4] = (short)f2bfu(u1.x); t[5] = (short)f2bfu(u1.y);
        t[6] = (short)f2bfu(u1.z); t[7] = (short)f2bfu(u1.w);
        a[mi] = t;
      }
#pragma unroll
      for (int ni = 0; ni < 4; ++ni) {
        int n = n0 + ni * 16 + lr;
        const float* wp = Bw + ((size_t)(n & 7) * HDIM + (n >> 3)) * IDIM + kk;
        float4 u0 = *reinterpret_cast<const float4*>(wp);
        float4 u1 = *reinterpret_cast<const float4*>(wp + 4);
        bf16x8 t;
        t[0] = (short)f2bfu(u0.x); t[1] = (short)f2bfu(u0.y);
        t[2] = (short)f2bfu(u0.z); t[3] = (short)f2bfu(u0.w);
        t[4] = (short)f2bfu(u1.x); t[5] = (short)f2bfu(u1.y);
        t[6] = (short)f2bfu(u1.z); t[7] = (short)f2bfu(u1.w);
        b[ni] = t;
      }
    }
#pragma unroll
    for (int mi = 0; mi < 4; ++mi)
#pragma unroll
      for (int ni = 0; ni < 4; ++ni)
        acc[mi][ni] = __builtin_amdgcn_mfma_f32_16x16x32_bf16(a[mi], b[ni], acc[mi][ni], 0, 0, 0);
  }

  const float alpha = alphap[0];
  const int rbase = (l >> 4) * 4;  // C/D: row = (lane>>4)*4 + reg, col = lane&15
  const int cofs = l & 15;
#pragma unroll
  for (int mi = 0; mi < 4; ++mi) {
#pragma unroll
    for (int ni = 0; ni < 4; ++ni) {
      const int n = n0 + ni * 16 + cofs;
      const float bias = PREP ? biasn[n] : Bb[(n & 7) * HDIM + (n >> 3)];
      const float sg = sigma[n];
#pragma unroll
      for (int r = 0; r < 4; ++r) {
        const int m = m0 + mi * 16 + rbase + r;
        const size_t idx = (size_t)m * NN + n;
        const float tot = acc[mi][ni][r] + bias;
        float v;
        if (alpha == 1.0f) {
          v = tanhf(tot + sg * noise[idx]);   // recurrence cancels at alpha==1
        } else {
          v = tot;                            // pre-activation; scan kernel finishes
        }
        act[idx] = v;
      }
    }
  }
}

// ---- general-alpha sequential scan (early-exit when alpha==1) ----
__global__ __launch_bounds__(256) void scan_kernel(const float* __restrict__ noise,
                                                   const float* __restrict__ sigma,
                                                   const float* __restrict__ alphap,
                                                   float* __restrict__ act) {
  const float alpha = alphap[0];
  if (alpha == 1.0f) return;
  const int id = blockIdx.x * 256 + threadIdx.x;  // 32768 chains = B * N
  const int b = id >> 11;
  const int n = id & (NN - 1);
  const float sg = sigma[n];
  float s = 0.f;
  for (int t = 0; t < TT; ++t) {
    const size_t idx = ((size_t)(t * BBATCH + b)) * NN + n;
    const float tot = act[idx];                 // gemm wrote pre-activation here
    const float ns = alpha * (tot - s) + s + sg * noise[idx];
    act[idx] = tanhf(ns);
    s = ns;
  }
}

// ---- readout: out[m][o] = sum_h act[m][h*8+o] * W_w[o][h] + W_b[o] ----
__global__ __launch_bounds__(256) void readout_kernel(const float* __restrict__ act,
                                                      const float* __restrict__ Ww,
                                                      const float* __restrict__ Wb,
                                                      float* __restrict__ out) {
  __shared__ float red[256][9];  // +1 pad breaks the stride-8 bank conflict
  const int m = blockIdx.x;
  const int j = threadIdx.x;     // j == h
  const float4 v0 = *reinterpret_cast<const float4*>(act + (size_t)m * NN + j * 8);
  const float4 v1 = *reinterpret_cast<const float4*>(act + (size_t)m * NN + j * 8 + 4);
  float av[8] = {v0.x, v0.y, v0.z, v0.w, v1.x, v1.y, v1.z, v1.w};
#pragma unroll
  for (int o = 0; o < 8; ++o) red[j][o] = av[o] * Ww[o * HDIM + j];
  __syncthreads();
  for (int s = 128; s >= 1; s >>= 1) {
    if (j < s) {
#pragma unroll
      for (int o = 0; o < 8; ++o) red[j][o] += red[j + s][o];
    }
    __syncthreads();
  }
  if (j < 8) out[(size_t)m * ODIM + j] = red[0][j] + Wb[j];
}

extern "C" void kernel_launch(void* const* d_in, const int* in_sizes, int n_in,
                              void* d_out, int out_size, void* d_ws, size_t ws_size,
                              hipStream_t stream) {
  const float* x     = (const float*)d_in[0];
  const float* noise = (const float*)d_in[1];
  const float* sigma = (const float*)d_in[2];
  const float* Bw    = (const float*)d_in[3];
  const float* Bb    = (const float*)d_in[4];
  const float* Ww    = (const float*)d_in[5];
  const float* Wb    = (const float*)d_in[6];
  const float* alpha = (const float*)d_in[7];

  float* out = (float*)d_out;                       // [T*B*O]
  float* act = out + (size_t)TT * BBATCH * ODIM;    // [T*B*H*O] (second output)

  const size_t xb_bytes = (size_t)MM * KK * 2;      // 16 MiB
  const size_t wb_bytes = (size_t)NN * KK * 2;      // 1 MiB
  const size_t need = xb_bytes + wb_bytes + (size_t)NN * 4;
  const bool prep = ws_size >= need;

  unsigned short* xb = (unsigned short*)d_ws;
  unsigned short* wb = (unsigned short*)((char*)d_ws + xb_bytes);
  float* biasn = (float*)((char*)d_ws + xb_bytes + wb_bytes);

  if (prep) {
    conv_x_kernel<<<(MM * KK / 4) / 256, 256, 0, stream>>>(x, xb);
    conv_w_kernel<<<NN, 64, 0, stream>>>(Bw, Bb, wb, biasn);
  }

  dim3 grid(NN / 128, MM / 128);  // (16, 256)
  if (prep) {
    gemm_kernel<true><<<grid, 256, 0, stream>>>(xb, wb, biasn, nullptr, nullptr, nullptr,
                                                noise, sigma, alpha, act);
  } else {
    gemm_kernel<false><<<grid, 256, 0, stream>>>(nullptr, nullptr, nullptr, x, Bw, Bb,
                                                 noise, sigma, alpha, act);
  }

  scan_kernel<<<(BBATCH * NN) / 256, 256, 0, stream>>>(noise, sigma, alpha, act);
  readout_kernel<<<MM, 256, 0, stream>>>(act, Ww, Wb, out);
}

// Round 2
// 331.162 us; speedup vs baseline: 1.3451x; 1.3451x over previous
//
#include <hip/hip_runtime.h>
#include <hip/hip_bf16.h>

// Problem constants (T,B,I,H,O) = (2048,16,256,256,8)
#define TT     2048
#define BBATCH 16
#define IDIM   256
#define HDIM   256
#define ODIM   8
#define MM (TT * BBATCH)   // 32768 rows (t*B + b)
#define NN (HDIM * ODIM)   // 2048 cols (h*8 + o)
#define KK IDIM            // 256

typedef __attribute__((ext_vector_type(8))) short bf16x8;
typedef __attribute__((ext_vector_type(4))) float f32x4;

__device__ __forceinline__ unsigned short f2bfu(float f) {
  __hip_bfloat16 h = __float2bfloat16(f);
  return *reinterpret_cast<unsigned short*>(&h);
}

// fast tanh: t = exp(-2|x|); r = (1-t)/(1+t); copysign. |err| ~1e-7, no overflow.
__device__ __forceinline__ float fast_tanh(float x) {
  float a = __builtin_fabsf(x);
  float t = __expf(-2.0f * a);
  float r = __fdividef(1.0f - t, 1.0f + t);
  return __builtin_copysignf(r, x);
}

// ---- prep: x (f32 [M][K]) -> bf16 [M][K] ----
__global__ __launch_bounds__(256) void conv_x_kernel(const float* __restrict__ x,
                                                     unsigned short* __restrict__ xb) {
  size_t id = (size_t)blockIdx.x * 256 + threadIdx.x;  // 4 elements each
  float4 v = reinterpret_cast<const float4*>(x)[id];
  ushort4 o;
  o.x = f2bfu(v.x); o.y = f2bfu(v.y); o.z = f2bfu(v.z); o.w = f2bfu(v.w);
  reinterpret_cast<ushort4*>(xb)[id] = o;
}

// ---- prep: B_w (f32 [O][H][I]) -> bf16 W[n=h*8+o][k], bias_n[n] = B_b[o][h] ----
__global__ __launch_bounds__(64) void conv_w_kernel(const float* __restrict__ Bw,
                                                    const float* __restrict__ Bb,
                                                    unsigned short* __restrict__ wb,
                                                    float* __restrict__ biasn) {
  int n = blockIdx.x;        // 0..2047
  int j = threadIdx.x;       // 0..63 (4 k-elements each)
  int o = n & 7, h = n >> 3;
  const float* src = Bw + ((size_t)o * HDIM + h) * IDIM;
  float4 v = reinterpret_cast<const float4*>(src)[j];
  ushort4 p;
  p.x = f2bfu(v.x); p.y = f2bfu(v.y); p.z = f2bfu(v.z); p.w = f2bfu(v.w);
  reinterpret_cast<ushort4*>(wb + (size_t)n * KK)[j] = p;
  if (j == 0) biasn[n] = Bb[o * HDIM + h];
}

// ---- main GEMM + fused epilogue ----
// C[m][n] = sum_k X[m][k] * W[n][k] + bias[n]
// Operand-swapped MFMA: D = mfma(W_frag, X_frag) so lane-held f32x4 runs along n
// -> epilogue noise loads / act stores are float4 (dwordx4).
// if alpha==1: act = tanh(C + sigma[n]*noise[m][n]); else act = C (scan finishes).
template <bool PREP>
__global__ __launch_bounds__(256) void gemm_kernel(
    const unsigned short* __restrict__ xb, const unsigned short* __restrict__ wb,
    const float* __restrict__ biasn,
    const float* __restrict__ xf, const float* __restrict__ Bw, const float* __restrict__ Bb,
    const float* __restrict__ noise, const float* __restrict__ sigma,
    const float* __restrict__ alphap,
    float* __restrict__ act) {
  const int tid = threadIdx.x;
  const int l = tid & 63;
  const int w = tid >> 6;              // 4 waves, 2x2
  const int wr = w >> 1, wc = w & 1;
  const int m0 = blockIdx.y * 128 + wr * 64;
  const int n0 = blockIdx.x * 128 + wc * 64;
  const int lr = l & 15, lg = l >> 4;

  f32x4 acc[4][4];  // [ni][mi]; lane: m = m0+mi*16+(l&15), n = n0+ni*16+(l>>4)*4+reg
#pragma unroll
  for (int ni = 0; ni < 4; ++ni)
#pragma unroll
    for (int mi = 0; mi < 4; ++mi) acc[ni][mi] = (f32x4){0.f, 0.f, 0.f, 0.f};

#pragma unroll
  for (int kt = 0; kt < KK / 32; ++kt) {
    const int kk = kt * 32 + lg * 8;   // this lane-group's 8-element k-chunk
    bf16x8 a[4], b[4];
    if constexpr (PREP) {
#pragma unroll
      for (int mi = 0; mi < 4; ++mi)
        a[mi] = *reinterpret_cast<const bf16x8*>(xb + (size_t)(m0 + mi * 16 + lr) * KK + kk);
#pragma unroll
      for (int ni = 0; ni < 4; ++ni)
        b[ni] = *reinterpret_cast<const bf16x8*>(wb + (size_t)(n0 + ni * 16 + lr) * KK + kk);
    } else {
#pragma unroll
      for (int mi = 0; mi < 4; ++mi) {
        const float* ap = xf + (size_t)(m0 + mi * 16 + lr) * KK + kk;
        float4 u0 = *reinterpret_cast<const float4*>(ap);
        float4 u1 = *reinterpret_cast<const float4*>(ap + 4);
        bf16x8 t;
        t[0] = (short)f2bfu(u0.x); t[1] = (short)f2bfu(u0.y);
        t[2] = (short)f2bfu(u0.z); t[3] = (short)f2bfu(u0.w);
        t[4] = (short)f2bfu(u1.x); t[5] = (short)f2bfu(u1.y);
        t[6] = (short)f2bfu(u1.z); t[7] = (short)f2bfu(u1.w);
        a[mi] = t;
      }
#pragma unroll
      for (int ni = 0; ni < 4; ++ni) {
        int n = n0 + ni * 16 + lr;
        const float* wp = Bw + ((size_t)(n & 7) * HDIM + (n >> 3)) * IDIM + kk;
        float4 u0 = *reinterpret_cast<const float4*>(wp);
        float4 u1 = *reinterpret_cast<const float4*>(wp + 4);
        bf16x8 t;
        t[0] = (short)f2bfu(u0.x); t[1] = (short)f2bfu(u0.y);
        t[2] = (short)f2bfu(u0.z); t[3] = (short)f2bfu(u0.w);
        t[4] = (short)f2bfu(u1.x); t[5] = (short)f2bfu(u1.y);
        t[6] = (short)f2bfu(u1.z); t[7] = (short)f2bfu(u1.w);
        b[ni] = t;
      }
    }
    // swapped operands: W-frag as A-operand, X-frag as B-operand -> D axis: reg = n
#pragma unroll
    for (int ni = 0; ni < 4; ++ni)
#pragma unroll
      for (int mi = 0; mi < 4; ++mi)
        acc[ni][mi] = __builtin_amdgcn_mfma_f32_16x16x32_bf16(b[ni], a[mi], acc[ni][mi], 0, 0, 0);
  }

  const float alpha = alphap[0];
  const int rb = lg * 4;               // n-offset base held in the f32x4
#pragma unroll
  for (int mi = 0; mi < 4; ++mi) {
    const int m = m0 + mi * 16 + lr;
    const float* __restrict__ nrow = noise + (size_t)m * NN;
    float* __restrict__ arow = act + (size_t)m * NN;
#pragma unroll
    for (int ni = 0; ni < 4; ++ni) {
      const int n = n0 + ni * 16 + rb;          // 4-aligned -> 16B-aligned addrs
      const float4 sg = *reinterpret_cast<const float4*>(sigma + n);
      float4 bs;
      if constexpr (PREP) {
        bs = *reinterpret_cast<const float4*>(biasn + n);
      } else {
        bs.x = Bb[((n + 0) & 7) * HDIM + ((n + 0) >> 3)];
        bs.y = Bb[((n + 1) & 7) * HDIM + ((n + 1) >> 3)];
        bs.z = Bb[((n + 2) & 7) * HDIM + ((n + 2) >> 3)];
        bs.w = Bb[((n + 3) & 7) * HDIM + ((n + 3) >> 3)];
      }
      const float4 nz = *reinterpret_cast<const float4*>(nrow + n);
      float4 v;
      v.x = acc[ni][mi][0] + bs.x;
      v.y = acc[ni][mi][1] + bs.y;
      v.z = acc[ni][mi][2] + bs.z;
      v.w = acc[ni][mi][3] + bs.w;
      if (alpha == 1.0f) {             // recurrence cancels at alpha==1
        v.x = fast_tanh(v.x + sg.x * nz.x);
        v.y = fast_tanh(v.y + sg.y * nz.y);
        v.z = fast_tanh(v.z + sg.z * nz.z);
        v.w = fast_tanh(v.w + sg.w * nz.w);
      }
      *reinterpret_cast<float4*>(arow + n) = v;
    }
  }
}

// ---- general-alpha sequential scan (early-exit when alpha==1) ----
__global__ __launch_bounds__(256) void scan_kernel(const float* __restrict__ noise,
                                                   const float* __restrict__ sigma,
                                                   const float* __restrict__ alphap,
                                                   float* __restrict__ act) {
  const float alpha = alphap[0];
  if (alpha == 1.0f) return;
  const int id = blockIdx.x * 256 + threadIdx.x;  // 32768 chains = B * N
  const int b = id >> 11;
  const int n = id & (NN - 1);
  const float sg = sigma[n];
  float s = 0.f;
  for (int t = 0; t < TT; ++t) {
    const size_t idx = ((size_t)(t * BBATCH + b)) * NN + n;
    const float tot = act[idx];                 // gemm wrote pre-activation here
    const float ns = alpha * (tot - s) + s + sg * noise[idx];
    act[idx] = tanhf(ns);
    s = ns;
  }
}

// ---- readout: out[m][o] = sum_h act[m][h*8+o] * W_w[o][h] + W_b[o] ----
__global__ __launch_bounds__(256) void readout_kernel(const float* __restrict__ act,
                                                      const float* __restrict__ Ww,
                                                      const float* __restrict__ Wb,
                                                      float* __restrict__ out) {
  __shared__ float red[256][9];  // +1 pad breaks the stride-8 bank conflict
  const int m = blockIdx.x;
  const int j = threadIdx.x;     // j == h
  const float4 v0 = *reinterpret_cast<const float4*>(act + (size_t)m * NN + j * 8);
  const float4 v1 = *reinterpret_cast<const float4*>(act + (size_t)m * NN + j * 8 + 4);
  float av[8] = {v0.x, v0.y, v0.z, v0.w, v1.x, v1.y, v1.z, v1.w};
#pragma unroll
  for (int o = 0; o < 8; ++o) red[j][o] = av[o] * Ww[o * HDIM + j];
  __syncthreads();
  for (int s = 128; s >= 1; s >>= 1) {
    if (j < s) {
#pragma unroll
      for (int o = 0; o < 8; ++o) red[j][o] += red[j + s][o];
    }
    __syncthreads();
  }
  if (j < 8) out[(size_t)m * ODIM + j] = red[0][j] + Wb[j];
}

extern "C" void kernel_launch(void* const* d_in, const int* in_sizes, int n_in,
                              void* d_out, int out_size, void* d_ws, size_t ws_size,
                              hipStream_t stream) {
  const float* x     = (const float*)d_in[0];
  const float* noise = (const float*)d_in[1];
  const float* sigma = (const float*)d_in[2];
  const float* Bw    = (const float*)d_in[3];
  const float* Bb    = (const float*)d_in[4];
  const float* Ww    = (const float*)d_in[5];
  const float* Wb    = (const float*)d_in[6];
  const float* alpha = (const float*)d_in[7];

  float* out = (float*)d_out;                       // [T*B*O]
  float* act = out + (size_t)TT * BBATCH * ODIM;    // [T*B*H*O] (second output)

  const size_t xb_bytes = (size_t)MM * KK * 2;      // 16 MiB
  const size_t wb_bytes = (size_t)NN * KK * 2;      // 1 MiB
  const size_t need = xb_bytes + wb_bytes + (size_t)NN * 4;
  const bool prep = ws_size >= need;

  unsigned short* xb = (unsigned short*)d_ws;
  unsigned short* wb = (unsigned short*)((char*)d_ws + xb_bytes);
  float* biasn = (float*)((char*)d_ws + xb_bytes + wb_bytes);

  if (prep) {
    conv_x_kernel<<<(MM * KK / 4) / 256, 256, 0, stream>>>(x, xb);
    conv_w_kernel<<<NN, 64, 0, stream>>>(Bw, Bb, wb, biasn);
  }

  dim3 grid(NN / 128, MM / 128);  // (16, 256)
  if (prep) {
    gemm_kernel<true><<<grid, 256, 0, stream>>>(xb, wb, biasn, nullptr, nullptr, nullptr,
                                                noise, sigma, alpha, act);
  } else {
    gemm_kernel<false><<<grid, 256, 0, stream>>>(nullptr, nullptr, nullptr, x, Bw, Bb,
                                                 noise, sigma, alpha, act);
  }

  scan_kernel<<<(BBATCH * NN) / 256, 256, 0, stream>>>(noise, sigma, alpha, act);
  readout_kernel<<<MM, 256, 0, stream>>>(act, Ww, Wb, out);
}

// Round 3
// 195.443 us; speedup vs baseline: 2.2792x; 1.6944x over previous
//
#include <hip/hip_runtime.h>
#include <hip/hip_bf16.h>

// Problem constants (T,B,I,H,O) = (2048,16,256,256,8)
#define TT     2048
#define BBATCH 16
#define IDIM   256
#define HDIM   256
#define ODIM   8
#define MM (TT * BBATCH)   // 32768 rows (t*B + b)
#define NN (HDIM * ODIM)   // 2048 cols (h*8 + o)
#define KK IDIM            // 256

typedef __attribute__((ext_vector_type(8))) short bf16x8;
typedef __attribute__((ext_vector_type(4))) float f32x4;
typedef unsigned int u32;

__device__ __forceinline__ unsigned short f2bfu(float f) {
  __hip_bfloat16 h = __float2bfloat16(f);
  return *reinterpret_cast<unsigned short*>(&h);
}

// fast tanh: t = exp(-2|x|); r = (1-t)/(1+t); copysign. |err| ~1e-7.
__device__ __forceinline__ float fast_tanh(float x) {
  float a = __builtin_fabsf(x);
  float t = __expf(-2.0f * a);
  float r = __fdividef(1.0f - t, 1.0f + t);
  return __builtin_copysignf(r, x);
}

__device__ __forceinline__ void gload16(const void* g, void* l) {
  __builtin_amdgcn_global_load_lds((const __attribute__((address_space(1))) u32*)g,
                                   (__attribute__((address_space(3))) u32*)l, 16, 0, 0);
}

// ---- prep: x (f32 [M][K]) -> bf16 [M][K], PRE-SWIZZLED within each 128B window:
// element (m,k) stored at row-byte (2k) ^ ((m&7)<<4). (XOR bits 4..6 < 128B window.)
__global__ __launch_bounds__(256) void conv_x_kernel(const float* __restrict__ x,
                                                     unsigned short* __restrict__ xb) {
  size_t id = (size_t)blockIdx.x * 256 + threadIdx.x;  // one ushort4 (4 elems) each
  int m = (int)(id >> 6);          // 64 groups of 4 per row (K=256)
  int g = (int)(id & 63);
  float4 v = reinterpret_cast<const float4*>(x)[id];
  ushort4 o;
  o.x = f2bfu(v.x); o.y = f2bfu(v.y); o.z = f2bfu(v.z); o.w = f2bfu(v.w);
  int dstbyte = (g * 8) ^ ((m & 7) << 4);
  *reinterpret_cast<ushort4*>(xb + (size_t)m * KK + dstbyte / 2) = o;
}

// ---- prep: B_w (f32 [O][H][I]) -> bf16 W[n=h*8+o][k] pre-swizzled, bias_n[n] ----
__global__ __launch_bounds__(64) void conv_w_kernel(const float* __restrict__ Bw,
                                                    const float* __restrict__ Bb,
                                                    unsigned short* __restrict__ wb,
                                                    float* __restrict__ biasn) {
  int n = blockIdx.x;        // 0..2047
  int j = threadIdx.x;       // 0..63 (4 k-elements each)
  int o = n & 7, h = n >> 3;
  const float* src = Bw + ((size_t)o * HDIM + h) * IDIM;
  float4 v = reinterpret_cast<const float4*>(src)[j];
  ushort4 p;
  p.x = f2bfu(v.x); p.y = f2bfu(v.y); p.z = f2bfu(v.z); p.w = f2bfu(v.w);
  int dstbyte = (j * 8) ^ ((n & 7) << 4);
  *reinterpret_cast<ushort4*>(wb + (size_t)n * KK + dstbyte / 2) = p;
  if (j == 0) biasn[n] = Bb[o * HDIM + h];
}

// ---- main GEMM, LDS-staged, fused epilogue ----
// C[m][n] = sum_k X[m][k]*W[n][k] + bias[n]; act = tanh(C + sigma*noise) at alpha==1.
// Pipeline: prefetch ALL epilogue operands to regs first, then 2-phase LDS K-loop
// (global_load_lds, raw s_barrier, counted vmcnt(8) so the prefetch stays in flight).
__global__ __launch_bounds__(256, 2) void gemm_lds_kernel(
    const unsigned short* __restrict__ xb, const unsigned short* __restrict__ wb,
    const float* __restrict__ biasn,
    const float* __restrict__ noise, const float* __restrict__ sigma,
    const float* __restrict__ alphap,
    float* __restrict__ act) {
  __shared__ __align__(16) char lds[65536];  // A:[2][16KB] @0, B:[2][16KB] @32KB

  const int tid = threadIdx.x;
  const int l = tid & 63;
  const int w = tid >> 6;              // 4 waves, 2x2
  const int wr = w >> 1, wc = w & 1;
  const int mbase = blockIdx.y * 128, nbase = blockIdx.x * 128;
  const int m0 = mbase + wr * 64, n0 = nbase + wc * 64;
  const int lr = l & 15, lg = l >> 4;
  const float alpha = alphap[0];

  // ---- epilogue operand prefetch (issued before anything else; 24 vmem ops) ----
  float4 nz[4][4], sg4[4], bs4[4];
#pragma unroll
  for (int ni = 0; ni < 4; ++ni) {
    sg4[ni] = *reinterpret_cast<const float4*>(sigma + n0 + ni * 16 + lg * 4);
    bs4[ni] = *reinterpret_cast<const float4*>(biasn + n0 + ni * 16 + lg * 4);
  }
#pragma unroll
  for (int mi = 0; mi < 4; ++mi) {
    const float* nrow = noise + (size_t)(m0 + mi * 16 + lr) * NN + n0 + lg * 4;
#pragma unroll
    for (int ni = 0; ni < 4; ++ni)
      nz[mi][ni] = *reinterpret_cast<const float4*>(nrow + ni * 16);
  }
  asm volatile("" ::: "memory");  // pin: prefetch issue-order before staging

  // ---- staging (global_load_lds, linear; sources are pre-swizzled) ----
  const int srow = w * 32 + (l >> 3);   // +r*8 per round
  const int spb = (l & 7) * 16;

  f32x4 acc[4][4];  // [ni][mi]; lane holds n = n0+ni*16+lg*4+reg, m = m0+mi*16+lr
#pragma unroll
  for (int ni = 0; ni < 4; ++ni)
#pragma unroll
    for (int mi = 0; mi < 4; ++mi) acc[ni][mi] = (f32x4){0.f, 0.f, 0.f, 0.f};

  auto STAGE = [&](int buf, int s) {  // 8 global_load_lds per wave
    const char* gA = (const char*)xb + (size_t)(mbase + srow) * 512 + s * 128 + spb;
    const char* gB = (const char*)wb + (size_t)(nbase + srow) * 512 + s * 128 + spb;
    char* lA = lds + buf * 16384 + w * 4096;          // wave-uniform dest base
    char* lB = lds + 32768 + buf * 16384 + w * 4096;
#pragma unroll
    for (int r = 0; r < 4; ++r) gload16(gA + (size_t)r * 8 * 512, lA + r * 1024);
#pragma unroll
    for (int r = 0; r < 4; ++r) gload16(gB + (size_t)r * 8 * 512, lB + r * 1024);
  };

  const int swz = (lr & 7) << 4;  // row&7 == lr&7 (row = 64*wr + 16*mi + lr)
  auto COMPUTE = [&](int buf) {
    const char* lA = lds + buf * 16384;
    const char* lB = lds + 32768 + buf * 16384;
#pragma unroll
    for (int kc = 0; kc < 2; ++kc) {
      const int cb = kc * 64 + lg * 16;
      const int cbs = cb ^ swz;
      bf16x8 a[4], b[4];
#pragma unroll
      for (int mi = 0; mi < 4; ++mi)
        a[mi] = *reinterpret_cast<const bf16x8*>(lA + (wr * 64 + mi * 16 + lr) * 128 + cbs);
#pragma unroll
      for (int ni = 0; ni < 4; ++ni)
        b[ni] = *reinterpret_cast<const bf16x8*>(lB + (wc * 64 + ni * 16 + lr) * 128 + cbs);
#pragma unroll
      for (int ni = 0; ni < 4; ++ni)
#pragma unroll
        for (int mi = 0; mi < 4; ++mi)
          acc[ni][mi] = __builtin_amdgcn_mfma_f32_16x16x32_bf16(b[ni], a[mi], acc[ni][mi], 0, 0, 0);
    }
  };

  STAGE(0, 0);
#pragma unroll
  for (int s = 0; s < 4; ++s) {
    if (s < 3) {
      STAGE((s + 1) & 1, s + 1);
      asm volatile("s_waitcnt vmcnt(8)" ::: "memory");  // stage(s) done; stage(s+1)+nothing else may fly
    } else {
      asm volatile("s_waitcnt vmcnt(0)" ::: "memory");
    }
    __builtin_amdgcn_s_barrier();
    COMPUTE(s & 1);
    __builtin_amdgcn_s_barrier();
  }

  // ---- fused epilogue (all operands already in registers) ----
  if (alpha == 1.0f) {
#pragma unroll
    for (int mi = 0; mi < 4; ++mi) {
      float* arow = act + (size_t)(m0 + mi * 16 + lr) * NN + n0 + lg * 4;
#pragma unroll
      for (int ni = 0; ni < 4; ++ni) {
        float4 v;
        v.x = fast_tanh(acc[ni][mi][0] + bs4[ni].x + sg4[ni].x * nz[mi][ni].x);
        v.y = fast_tanh(acc[ni][mi][1] + bs4[ni].y + sg4[ni].y * nz[mi][ni].y);
        v.z = fast_tanh(acc[ni][mi][2] + bs4[ni].z + sg4[ni].z * nz[mi][ni].z);
        v.w = fast_tanh(acc[ni][mi][3] + bs4[ni].w + sg4[ni].w * nz[mi][ni].w);
        *reinterpret_cast<float4*>(arow + ni * 16) = v;
      }
    }
  } else {
#pragma unroll
    for (int mi = 0; mi < 4; ++mi) {
      float* arow = act + (size_t)(m0 + mi * 16 + lr) * NN + n0 + lg * 4;
#pragma unroll
      for (int ni = 0; ni < 4; ++ni) {
        float4 v;
        v.x = acc[ni][mi][0] + bs4[ni].x;
        v.y = acc[ni][mi][1] + bs4[ni].y;
        v.z = acc[ni][mi][2] + bs4[ni].z;
        v.w = acc[ni][mi][3] + bs4[ni].w;
        *reinterpret_cast<float4*>(arow + ni * 16) = v;   // pre-activation; scan finishes
      }
    }
  }
}

// ---- fallback GEMM (no workspace): direct f32 loads, inline bf16 convert ----
__global__ __launch_bounds__(256) void gemm_direct_kernel(
    const float* __restrict__ xf, const float* __restrict__ Bw, const float* __restrict__ Bb,
    const float* __restrict__ noise, const float* __restrict__ sigma,
    const float* __restrict__ alphap,
    float* __restrict__ act) {
  const int tid = threadIdx.x;
  const int l = tid & 63;
  const int w = tid >> 6;
  const int wr = w >> 1, wc = w & 1;
  const int m0 = blockIdx.y * 128 + wr * 64;
  const int n0 = blockIdx.x * 128 + wc * 64;
  const int lr = l & 15, lg = l >> 4;

  f32x4 acc[4][4];
#pragma unroll
  for (int ni = 0; ni < 4; ++ni)
#pragma unroll
    for (int mi = 0; mi < 4; ++mi) acc[ni][mi] = (f32x4){0.f, 0.f, 0.f, 0.f};

#pragma unroll
  for (int kt = 0; kt < KK / 32; ++kt) {
    const int kk = kt * 32 + lg * 8;
    bf16x8 a[4], b[4];
#pragma unroll
    for (int mi = 0; mi < 4; ++mi) {
      const float* ap = xf + (size_t)(m0 + mi * 16 + lr) * KK + kk;
      float4 u0 = *reinterpret_cast<const float4*>(ap);
      float4 u1 = *reinterpret_cast<const float4*>(ap + 4);
      bf16x8 t;
      t[0] = (short)f2bfu(u0.x); t[1] = (short)f2bfu(u0.y);
      t[2] = (short)f2bfu(u0.z); t[3] = (short)f2bfu(u0.w);
      t[4] = (short)f2bfu(u1.x); t[5] = (short)f2bfu(u1.y);
      t[6] = (short)f2bfu(u1.z); t[7] = (short)f2bfu(u1.w);
      a[mi] = t;
    }
#pragma unroll
    for (int ni = 0; ni < 4; ++ni) {
      int n = n0 + ni * 16 + lr;
      const float* wp = Bw + ((size_t)(n & 7) * HDIM + (n >> 3)) * IDIM + kk;
      float4 u0 = *reinterpret_cast<const float4*>(wp);
      float4 u1 = *reinterpret_cast<const float4*>(wp + 4);
      bf16x8 t;
      t[0] = (short)f2bfu(u0.x); t[1] = (short)f2bfu(u0.y);
      t[2] = (short)f2bfu(u0.z); t[3] = (short)f2bfu(u0.w);
      t[4] = (short)f2bfu(u1.x); t[5] = (short)f2bfu(u1.y);
      t[6] = (short)f2bfu(u1.z); t[7] = (short)f2bfu(u1.w);
      b[ni] = t;
    }
#pragma unroll
    for (int ni = 0; ni < 4; ++ni)
#pragma unroll
      for (int mi = 0; mi < 4; ++mi)
        acc[ni][mi] = __builtin_amdgcn_mfma_f32_16x16x32_bf16(b[ni], a[mi], acc[ni][mi], 0, 0, 0);
  }

  const float alpha = alphap[0];
#pragma unroll
  for (int mi = 0; mi < 4; ++mi) {
    const int m = m0 + mi * 16 + lr;
    const float* nrow = noise + (size_t)m * NN;
    float* arow = act + (size_t)m * NN;
#pragma unroll
    for (int ni = 0; ni < 4; ++ni) {
      const int n = n0 + ni * 16 + lg * 4;
      const float4 sg = *reinterpret_cast<const float4*>(sigma + n);
      float4 bs;
      bs.x = Bb[((n + 0) & 7) * HDIM + ((n + 0) >> 3)];
      bs.y = Bb[((n + 1) & 7) * HDIM + ((n + 1) >> 3)];
      bs.z = Bb[((n + 2) & 7) * HDIM + ((n + 2) >> 3)];
      bs.w = Bb[((n + 3) & 7) * HDIM + ((n + 3) >> 3)];
      const float4 nzv = *reinterpret_cast<const float4*>(nrow + n);
      float4 v;
      v.x = acc[ni][mi][0] + bs.x;
      v.y = acc[ni][mi][1] + bs.y;
      v.z = acc[ni][mi][2] + bs.z;
      v.w = acc[ni][mi][3] + bs.w;
      if (alpha == 1.0f) {
        v.x = fast_tanh(v.x + sg.x * nzv.x);
        v.y = fast_tanh(v.y + sg.y * nzv.y);
        v.z = fast_tanh(v.z + sg.z * nzv.z);
        v.w = fast_tanh(v.w + sg.w * nzv.w);
      }
      *reinterpret_cast<float4*>(arow + n) = v;
    }
  }
}

// ---- general-alpha sequential scan (early-exit when alpha==1) ----
__global__ __launch_bounds__(256) void scan_kernel(const float* __restrict__ noise,
                                                   const float* __restrict__ sigma,
                                                   const float* __restrict__ alphap,
                                                   float* __restrict__ act) {
  const float alpha = alphap[0];
  if (alpha == 1.0f) return;
  const int id = blockIdx.x * 256 + threadIdx.x;  // 32768 chains = B * N
  const int b = id >> 11;
  const int n = id & (NN - 1);
  const float sg = sigma[n];
  float s = 0.f;
  for (int t = 0; t < TT; ++t) {
    const size_t idx = ((size_t)(t * BBATCH + b)) * NN + n;
    const float tot = act[idx];
    const float ns = alpha * (tot - s) + s + sg * noise[idx];
    act[idx] = tanhf(ns);
    s = ns;
  }
}

// ---- readout: out[m][o] = sum_h act[m][h*8+o] * W_w[o][h] + W_b[o] ----
__global__ __launch_bounds__(256) void readout_kernel(const float* __restrict__ act,
                                                      const float* __restrict__ Ww,
                                                      const float* __restrict__ Wb,
                                                      float* __restrict__ out) {
  __shared__ float red[256][9];
  const int m = blockIdx.x;
  const int j = threadIdx.x;     // j == h
  const float4 v0 = *reinterpret_cast<const float4*>(act + (size_t)m * NN + j * 8);
  const float4 v1 = *reinterpret_cast<const float4*>(act + (size_t)m * NN + j * 8 + 4);
  float av[8] = {v0.x, v0.y, v0.z, v0.w, v1.x, v1.y, v1.z, v1.w};
#pragma unroll
  for (int o = 0; o < 8; ++o) red[j][o] = av[o] * Ww[o * HDIM + j];
  __syncthreads();
  for (int s = 128; s >= 1; s >>= 1) {
    if (j < s) {
#pragma unroll
      for (int o = 0; o < 8; ++o) red[j][o] += red[j + s][o];
    }
    __syncthreads();
  }
  if (j < 8) out[(size_t)m * ODIM + j] = red[0][j] + Wb[j];
}

extern "C" void kernel_launch(void* const* d_in, const int* in_sizes, int n_in,
                              void* d_out, int out_size, void* d_ws, size_t ws_size,
                              hipStream_t stream) {
  const float* x     = (const float*)d_in[0];
  const float* noise = (const float*)d_in[1];
  const float* sigma = (const float*)d_in[2];
  const float* Bw    = (const float*)d_in[3];
  const float* Bb    = (const float*)d_in[4];
  const float* Ww    = (const float*)d_in[5];
  const float* Wb    = (const float*)d_in[6];
  const float* alpha = (const float*)d_in[7];

  float* out = (float*)d_out;                       // [T*B*O]
  float* act = out + (size_t)TT * BBATCH * ODIM;    // [T*B*H*O] (second output)

  const size_t xb_bytes = (size_t)MM * KK * 2;      // 16 MiB
  const size_t wb_bytes = (size_t)NN * KK * 2;      // 1 MiB
  const size_t need = xb_bytes + wb_bytes + (size_t)NN * 4;
  const bool prep = ws_size >= need;

  unsigned short* xb = (unsigned short*)d_ws;
  unsigned short* wb = (unsigned short*)((char*)d_ws + xb_bytes);
  float* biasn = (float*)((char*)d_ws + xb_bytes + wb_bytes);

  dim3 grid(NN / 128, MM / 128);  // (16, 256)
  if (prep) {
    conv_x_kernel<<<(MM * KK / 4) / 256, 256, 0, stream>>>(x, xb);
    conv_w_kernel<<<NN, 64, 0, stream>>>(Bw, Bb, wb, biasn);
    gemm_lds_kernel<<<grid, 256, 0, stream>>>(xb, wb, biasn, noise, sigma, alpha, act);
  } else {
    gemm_direct_kernel<<<grid, 256, 0, stream>>>(x, Bw, Bb, noise, sigma, alpha, act);
  }

  scan_kernel<<<(BBATCH * NN) / 256, 256, 0, stream>>>(noise, sigma, alpha, act);
  readout_kernel<<<MM, 256, 0, stream>>>(act, Ww, Wb, out);
}

// Round 4
// 166.795 us; speedup vs baseline: 2.6707x; 1.1718x over previous
//
#include <hip/hip_runtime.h>
#include <hip/hip_bf16.h>

// Problem constants (T,B,I,H,O) = (2048,16,256,256,8)
#define TT     2048
#define BBATCH 16
#define IDIM   256
#define HDIM   256
#define ODIM   8
#define MM (TT * BBATCH)   // 32768 rows (t*B + b)
#define NN (HDIM * ODIM)   // 2048 cols (h*8 + o)
#define KK IDIM            // 256
#define NBLK (NN / 128)    // 16 n-blocks -> partial readout slices

typedef __attribute__((ext_vector_type(8))) short bf16x8;
typedef __attribute__((ext_vector_type(4))) float f32x4;
typedef unsigned int u32;

__device__ __forceinline__ unsigned short f2bfu(float f) {
  __hip_bfloat16 h = __float2bfloat16(f);
  return *reinterpret_cast<unsigned short*>(&h);
}

// fast tanh: t = exp(-2|x|); r = (1-t)/(1+t); copysign. |err| ~1e-7.
__device__ __forceinline__ float fast_tanh(float x) {
  float a = __builtin_fabsf(x);
  float t = __expf(-2.0f * a);
  float r = __fdividef(1.0f - t, 1.0f + t);
  return __builtin_copysignf(r, x);
}

__device__ __forceinline__ void gload16(const void* g, void* l) {
  __builtin_amdgcn_global_load_lds((const __attribute__((address_space(1))) u32*)g,
                                   (__attribute__((address_space(3))) u32*)l, 16, 0, 0);
}

// ---- prep: x (f32 [M][K]) -> bf16 [M][K], PRE-SWIZZLED within each 128B window:
// element (m,k) stored at row-byte (2k) ^ ((m&7)<<4).
__global__ __launch_bounds__(256) void conv_x_kernel(const float* __restrict__ x,
                                                     unsigned short* __restrict__ xb) {
  size_t id = (size_t)blockIdx.x * 256 + threadIdx.x;  // one ushort4 (4 elems) each
  int m = (int)(id >> 6);          // 64 groups of 4 per row (K=256)
  int g = (int)(id & 63);
  float4 v = reinterpret_cast<const float4*>(x)[id];
  ushort4 o;
  o.x = f2bfu(v.x); o.y = f2bfu(v.y); o.z = f2bfu(v.z); o.w = f2bfu(v.w);
  int dstbyte = (g * 8) ^ ((m & 7) << 4);
  *reinterpret_cast<ushort4*>(xb + (size_t)m * KK + dstbyte / 2) = o;
}

// ---- prep: B_w -> bf16 W[n=h*8+o][k] pre-swizzled; bias_n[n]; Wwn[n]=W_w[o,h] ----
__global__ __launch_bounds__(64) void conv_w_kernel(const float* __restrict__ Bw,
                                                    const float* __restrict__ Bb,
                                                    const float* __restrict__ Ww,
                                                    unsigned short* __restrict__ wb,
                                                    float* __restrict__ biasn,
                                                    float* __restrict__ wwn) {
  int n = blockIdx.x;        // 0..2047
  int j = threadIdx.x;       // 0..63 (4 k-elements each)
  int o = n & 7, h = n >> 3;
  const float* src = Bw + ((size_t)o * HDIM + h) * IDIM;
  float4 v = reinterpret_cast<const float4*>(src)[j];
  ushort4 p;
  p.x = f2bfu(v.x); p.y = f2bfu(v.y); p.z = f2bfu(v.z); p.w = f2bfu(v.w);
  int dstbyte = (j * 8) ^ ((n & 7) << 4);
  *reinterpret_cast<ushort4*>(wb + (size_t)n * KK + dstbyte / 2) = p;
  if (j == 0) biasn[n] = Bb[o * HDIM + h];
  if (j == 32) wwn[n] = Ww[o * HDIM + h];
}

// ---- main GEMM, LDS-staged, fused epilogue (+ optional fused readout partials) ----
template <bool FUSE>
__global__ __launch_bounds__(256, 2) void gemm_lds_kernel(
    const unsigned short* __restrict__ xb, const unsigned short* __restrict__ wb,
    const float* __restrict__ biasn, const float* __restrict__ wwn,
    const float* __restrict__ noise, const float* __restrict__ sigma,
    const float* __restrict__ alphap,
    float* __restrict__ act, float* __restrict__ partial) {
  __shared__ __align__(16) char lds[65536];  // A:[2][16KB] @0, B:[2][16KB] @32KB

  const int tid = threadIdx.x;
  const int l = tid & 63;
  const int w = tid >> 6;              // 4 waves, 2x2
  const int wr = w >> 1, wc = w & 1;
  const int mbase = blockIdx.y * 128, nbase = blockIdx.x * 128;
  const int m0 = mbase + wr * 64, n0 = nbase + wc * 64;
  const int lr = l & 15, lg = l >> 4;
  const float alpha = alphap[0];

  // ---- epilogue operand prefetch (issued before staging; stays in flight under K) ----
  float4 nz[4][4], sg4[4], bs4[4];
#pragma unroll
  for (int ni = 0; ni < 4; ++ni) {
    sg4[ni] = *reinterpret_cast<const float4*>(sigma + n0 + ni * 16 + lg * 4);
    bs4[ni] = *reinterpret_cast<const float4*>(biasn + n0 + ni * 16 + lg * 4);
  }
#pragma unroll
  for (int mi = 0; mi < 4; ++mi) {
    const float* nrow = noise + (size_t)(m0 + mi * 16 + lr) * NN + n0 + lg * 4;
#pragma unroll
    for (int ni = 0; ni < 4; ++ni)
      nz[mi][ni] = *reinterpret_cast<const float4*>(nrow + ni * 16);
  }
  asm volatile("" ::: "memory");  // pin prefetch issue-order before staging

  const int srow = w * 32 + (l >> 3);
  const int spb = (l & 7) * 16;

  f32x4 acc[4][4];  // [ni][mi]; lane: n = n0+ni*16+lg*4+reg, m = m0+mi*16+lr
#pragma unroll
  for (int ni = 0; ni < 4; ++ni)
#pragma unroll
    for (int mi = 0; mi < 4; ++mi) acc[ni][mi] = (f32x4){0.f, 0.f, 0.f, 0.f};

  auto STAGE = [&](int buf, int s) {  // 8 global_load_lds per wave
    const char* gA = (const char*)xb + (size_t)(mbase + srow) * 512 + s * 128 + spb;
    const char* gB = (const char*)wb + (size_t)(nbase + srow) * 512 + s * 128 + spb;
    char* lA = lds + buf * 16384 + w * 4096;
    char* lB = lds + 32768 + buf * 16384 + w * 4096;
#pragma unroll
    for (int r = 0; r < 4; ++r) gload16(gA + (size_t)r * 8 * 512, lA + r * 1024);
#pragma unroll
    for (int r = 0; r < 4; ++r) gload16(gB + (size_t)r * 8 * 512, lB + r * 1024);
  };

  const int swz = (lr & 7) << 4;
  auto COMPUTE = [&](int buf) {
    const char* lA = lds + buf * 16384;
    const char* lB = lds + 32768 + buf * 16384;
#pragma unroll
    for (int kc = 0; kc < 2; ++kc) {
      const int cbs = (kc * 64 + lg * 16) ^ swz;
      bf16x8 a[4], b[4];
#pragma unroll
      for (int mi = 0; mi < 4; ++mi)
        a[mi] = *reinterpret_cast<const bf16x8*>(lA + (wr * 64 + mi * 16 + lr) * 128 + cbs);
#pragma unroll
      for (int ni = 0; ni < 4; ++ni)
        b[ni] = *reinterpret_cast<const bf16x8*>(lB + (wc * 64 + ni * 16 + lr) * 128 + cbs);
#pragma unroll
      for (int ni = 0; ni < 4; ++ni)
#pragma unroll
        for (int mi = 0; mi < 4; ++mi)
          acc[ni][mi] = __builtin_amdgcn_mfma_f32_16x16x32_bf16(b[ni], a[mi], acc[ni][mi], 0, 0, 0);
    }
  };

  STAGE(0, 0);
#pragma unroll
  for (int s = 0; s < 4; ++s) {
    if (s < 3) {
      STAGE((s + 1) & 1, s + 1);
      asm volatile("s_waitcnt vmcnt(8)" ::: "memory");
    } else {
      asm volatile("s_waitcnt vmcnt(0)" ::: "memory");
    }
    __builtin_amdgcn_s_barrier();
    COMPUTE(s & 1);
    __builtin_amdgcn_s_barrier();
  }

  // ---- fused epilogue ----
  if (alpha == 1.0f) {
    float4 ww4[4];
    f32x4 pp[4];  // per-thread readout partial over o = (lg&1)*4 .. +3
#pragma unroll
    for (int ni = 0; ni < 4; ++ni)
      ww4[ni] = *reinterpret_cast<const float4*>(wwn + n0 + ni * 16 + lg * 4);
#pragma unroll
    for (int mi = 0; mi < 4; ++mi) pp[mi] = (f32x4){0.f, 0.f, 0.f, 0.f};

#pragma unroll
    for (int mi = 0; mi < 4; ++mi) {
      float* arow = act + (size_t)(m0 + mi * 16 + lr) * NN + n0 + lg * 4;
#pragma unroll
      for (int ni = 0; ni < 4; ++ni) {
        float4 v;
        v.x = fast_tanh(acc[ni][mi][0] + bs4[ni].x + sg4[ni].x * nz[mi][ni].x);
        v.y = fast_tanh(acc[ni][mi][1] + bs4[ni].y + sg4[ni].y * nz[mi][ni].y);
        v.z = fast_tanh(acc[ni][mi][2] + bs4[ni].z + sg4[ni].z * nz[mi][ni].z);
        v.w = fast_tanh(acc[ni][mi][3] + bs4[ni].w + sg4[ni].w * nz[mi][ni].w);
        *reinterpret_cast<float4*>(arow + ni * 16) = v;
        if constexpr (FUSE) {
          pp[mi][0] += v.x * ww4[ni].x;
          pp[mi][1] += v.y * ww4[ni].y;
          pp[mi][2] += v.z * ww4[ni].z;
          pp[mi][3] += v.w * ww4[ni].w;
        }
      }
    }

    if constexpr (FUSE) {
      // LDS cross-wave/cross-lane reduce of partials (reuse staging LDS).
      f32x4* red = reinterpret_cast<f32x4*>(lds);  // [w][mi][lr][lg]
      __syncthreads();  // staging LDS free (all ds_reads consumed pre-barrier)
#pragma unroll
      for (int mi = 0; mi < 4; ++mi)
        red[((w * 4 + mi) * 16 + lr) * 4 + lg] = pp[mi];
      __syncthreads();
      // thread t -> (wr2, mi, lr2, oh); sum 4 slots: wc in {0,1} x lg in {oh, oh+2}
      const int t = tid;
      const int wr2 = t >> 7, mi2 = (t >> 5) & 3, lr2 = (t >> 1) & 15, oh = t & 1;
      f32x4 s0 = red[(((wr2 * 2 + 0) * 4 + mi2) * 16 + lr2) * 4 + oh];
      f32x4 s1 = red[(((wr2 * 2 + 0) * 4 + mi2) * 16 + lr2) * 4 + oh + 2];
      f32x4 s2 = red[(((wr2 * 2 + 1) * 4 + mi2) * 16 + lr2) * 4 + oh];
      f32x4 s3 = red[(((wr2 * 2 + 1) * 4 + mi2) * 16 + lr2) * 4 + oh + 2];
      f32x4 sm = s0 + s1 + s2 + s3;
      const int m = mbase + wr2 * 64 + mi2 * 16 + lr2;
      float4 outv = {sm[0], sm[1], sm[2], sm[3]};
      *reinterpret_cast<float4*>(partial + ((size_t)m * NBLK + blockIdx.x) * 8 + oh * 4) = outv;
    }
  } else {
#pragma unroll
    for (int mi = 0; mi < 4; ++mi) {
      float* arow = act + (size_t)(m0 + mi * 16 + lr) * NN + n0 + lg * 4;
#pragma unroll
      for (int ni = 0; ni < 4; ++ni) {
        float4 v;
        v.x = acc[ni][mi][0] + bs4[ni].x;
        v.y = acc[ni][mi][1] + bs4[ni].y;
        v.z = acc[ni][mi][2] + bs4[ni].z;
        v.w = acc[ni][mi][3] + bs4[ni].w;
        *reinterpret_cast<float4*>(arow + ni * 16) = v;   // pre-activation; scan finishes
      }
    }
  }
}

// ---- reduce partials -> out (alpha==1 path only; deterministic fixed-order sum) ----
__global__ __launch_bounds__(256) void reduce_kernel(const float* __restrict__ partial,
                                                     const float* __restrict__ Wb,
                                                     const float* __restrict__ alphap,
                                                     float* __restrict__ out) {
  if (alphap[0] != 1.0f) return;
  const int gid = blockIdx.x * 256 + threadIdx.x;  // 65536 = MM * 2
  const int m = gid >> 1, oh = gid & 1;
  const float4 wb4 = *reinterpret_cast<const float4*>(Wb + oh * 4);
  float4 s = {wb4.x, wb4.y, wb4.z, wb4.w};
  const float* p = partial + (size_t)m * NBLK * 8 + oh * 4;
#pragma unroll
  for (int nb = 0; nb < NBLK; ++nb) {
    const float4 v = *reinterpret_cast<const float4*>(p + nb * 8);
    s.x += v.x; s.y += v.y; s.z += v.z; s.w += v.w;
  }
  *reinterpret_cast<float4*>(out + (size_t)m * ODIM + oh * 4) = s;
}

// ---- fallback GEMM (no workspace): direct f32 loads, inline bf16 convert ----
__global__ __launch_bounds__(256) void gemm_direct_kernel(
    const float* __restrict__ xf, const float* __restrict__ Bw, const float* __restrict__ Bb,
    const float* __restrict__ noise, const float* __restrict__ sigma,
    const float* __restrict__ alphap,
    float* __restrict__ act) {
  const int tid = threadIdx.x;
  const int l = tid & 63;
  const int w = tid >> 6;
  const int wr = w >> 1, wc = w & 1;
  const int m0 = blockIdx.y * 128 + wr * 64;
  const int n0 = blockIdx.x * 128 + wc * 64;
  const int lr = l & 15, lg = l >> 4;

  f32x4 acc[4][4];
#pragma unroll
  for (int ni = 0; ni < 4; ++ni)
#pragma unroll
    for (int mi = 0; mi < 4; ++mi) acc[ni][mi] = (f32x4){0.f, 0.f, 0.f, 0.f};

#pragma unroll
  for (int kt = 0; kt < KK / 32; ++kt) {
    const int kk = kt * 32 + lg * 8;
    bf16x8 a[4], b[4];
#pragma unroll
    for (int mi = 0; mi < 4; ++mi) {
      const float* ap = xf + (size_t)(m0 + mi * 16 + lr) * KK + kk;
      float4 u0 = *reinterpret_cast<const float4*>(ap);
      float4 u1 = *reinterpret_cast<const float4*>(ap + 4);
      bf16x8 t;
      t[0] = (short)f2bfu(u0.x); t[1] = (short)f2bfu(u0.y);
      t[2] = (short)f2bfu(u0.z); t[3] = (short)f2bfu(u0.w);
      t[4] = (short)f2bfu(u1.x); t[5] = (short)f2bfu(u1.y);
      t[6] = (short)f2bfu(u1.z); t[7] = (short)f2bfu(u1.w);
      a[mi] = t;
    }
#pragma unroll
    for (int ni = 0; ni < 4; ++ni) {
      int n = n0 + ni * 16 + lr;
      const float* wp = Bw + ((size_t)(n & 7) * HDIM + (n >> 3)) * IDIM + kk;
      float4 u0 = *reinterpret_cast<const float4*>(wp);
      float4 u1 = *reinterpret_cast<const float4*>(wp + 4);
      bf16x8 t;
      t[0] = (short)f2bfu(u0.x); t[1] = (short)f2bfu(u0.y);
      t[2] = (short)f2bfu(u0.z); t[3] = (short)f2bfu(u0.w);
      t[4] = (short)f2bfu(u1.x); t[5] = (short)f2bfu(u1.y);
      t[6] = (short)f2bfu(u1.z); t[7] = (short)f2bfu(u1.w);
      b[ni] = t;
    }
#pragma unroll
    for (int ni = 0; ni < 4; ++ni)
#pragma unroll
      for (int mi = 0; mi < 4; ++mi)
        acc[ni][mi] = __builtin_amdgcn_mfma_f32_16x16x32_bf16(b[ni], a[mi], acc[ni][mi], 0, 0, 0);
  }

  const float alpha = alphap[0];
#pragma unroll
  for (int mi = 0; mi < 4; ++mi) {
    const int m = m0 + mi * 16 + lr;
    const float* nrow = noise + (size_t)m * NN;
    float* arow = act + (size_t)m * NN;
#pragma unroll
    for (int ni = 0; ni < 4; ++ni) {
      const int n = n0 + ni * 16 + lg * 4;
      const float4 sg = *reinterpret_cast<const float4*>(sigma + n);
      float4 bs;
      bs.x = Bb[((n + 0) & 7) * HDIM + ((n + 0) >> 3)];
      bs.y = Bb[((n + 1) & 7) * HDIM + ((n + 1) >> 3)];
      bs.z = Bb[((n + 2) & 7) * HDIM + ((n + 2) >> 3)];
      bs.w = Bb[((n + 3) & 7) * HDIM + ((n + 3) >> 3)];
      const float4 nzv = *reinterpret_cast<const float4*>(nrow + n);
      float4 v;
      v.x = acc[ni][mi][0] + bs.x;
      v.y = acc[ni][mi][1] + bs.y;
      v.z = acc[ni][mi][2] + bs.z;
      v.w = acc[ni][mi][3] + bs.w;
      if (alpha == 1.0f) {
        v.x = fast_tanh(v.x + sg.x * nzv.x);
        v.y = fast_tanh(v.y + sg.y * nzv.y);
        v.z = fast_tanh(v.z + sg.z * nzv.z);
        v.w = fast_tanh(v.w + sg.w * nzv.w);
      }
      *reinterpret_cast<float4*>(arow + n) = v;
    }
  }
}

// ---- general-alpha sequential scan (early-exit when alpha==1) ----
__global__ __launch_bounds__(256) void scan_kernel(const float* __restrict__ noise,
                                                   const float* __restrict__ sigma,
                                                   const float* __restrict__ alphap,
                                                   float* __restrict__ act) {
  const float alpha = alphap[0];
  if (alpha == 1.0f) return;
  const int id = blockIdx.x * 256 + threadIdx.x;
  const int b = id >> 11;
  const int n = id & (NN - 1);
  const float sg = sigma[n];
  float s = 0.f;
  for (int t = 0; t < TT; ++t) {
    const size_t idx = ((size_t)(t * BBATCH + b)) * NN + n;
    const float tot = act[idx];
    const float ns = alpha * (tot - s) + s + sg * noise[idx];
    act[idx] = tanhf(ns);
    s = ns;
  }
}

// ---- full readout from act (fallback; skipped when fused && alpha==1) ----
__global__ __launch_bounds__(256) void readout_kernel(const float* __restrict__ act,
                                                      const float* __restrict__ Ww,
                                                      const float* __restrict__ Wb,
                                                      const float* __restrict__ alphap,
                                                      int fused,
                                                      float* __restrict__ out) {
  if (fused && alphap[0] == 1.0f) return;
  __shared__ float red[256][9];
  const int m = blockIdx.x;
  const int j = threadIdx.x;     // j == h
  const float4 v0 = *reinterpret_cast<const float4*>(act + (size_t)m * NN + j * 8);
  const float4 v1 = *reinterpret_cast<const float4*>(act + (size_t)m * NN + j * 8 + 4);
  float av[8] = {v0.x, v0.y, v0.z, v0.w, v1.x, v1.y, v1.z, v1.w};
#pragma unroll
  for (int o = 0; o < 8; ++o) red[j][o] = av[o] * Ww[o * HDIM + j];
  __syncthreads();
  for (int s = 128; s >= 1; s >>= 1) {
    if (j < s) {
#pragma unroll
      for (int o = 0; o < 8; ++o) red[j][o] += red[j + s][o];
    }
    __syncthreads();
  }
  if (j < 8) out[(size_t)m * ODIM + j] = red[0][j] + Wb[j];
}

extern "C" void kernel_launch(void* const* d_in, const int* in_sizes, int n_in,
                              void* d_out, int out_size, void* d_ws, size_t ws_size,
                              hipStream_t stream) {
  const float* x     = (const float*)d_in[0];
  const float* noise = (const float*)d_in[1];
  const float* sigma = (const float*)d_in[2];
  const float* Bw    = (const float*)d_in[3];
  const float* Bb    = (const float*)d_in[4];
  const float* Ww    = (const float*)d_in[5];
  const float* Wb    = (const float*)d_in[6];
  const float* alpha = (const float*)d_in[7];

  float* out = (float*)d_out;                       // [T*B*O]
  float* act = out + (size_t)TT * BBATCH * ODIM;    // [T*B*H*O] (second output)

  const size_t xb_bytes = (size_t)MM * KK * 2;      // 16 MiB
  const size_t wb_bytes = (size_t)NN * KK * 2;      // 1 MiB
  const size_t bias_bytes = (size_t)NN * 4;
  const size_t wwn_bytes = (size_t)NN * 4;
  const size_t part_bytes = (size_t)MM * NBLK * 8 * 4;  // 16 MiB
  const size_t need_prep = xb_bytes + wb_bytes + bias_bytes + wwn_bytes;
  const size_t need_fuse = need_prep + part_bytes;
  const bool prep = ws_size >= need_prep;
  const bool fuse = ws_size >= need_fuse;

  unsigned short* xb = (unsigned short*)d_ws;
  unsigned short* wb = (unsigned short*)((char*)d_ws + xb_bytes);
  float* biasn = (float*)((char*)d_ws + xb_bytes + wb_bytes);
  float* wwn   = (float*)((char*)d_ws + xb_bytes + wb_bytes + bias_bytes);
  float* part  = (float*)((char*)d_ws + need_prep);

  dim3 grid(NN / 128, MM / 128);  // (16, 256)
  if (prep) {
    conv_x_kernel<<<(MM * KK / 4) / 256, 256, 0, stream>>>(x, xb);
    conv_w_kernel<<<NN, 64, 0, stream>>>(Bw, Bb, Ww, wb, biasn, wwn);
    if (fuse) {
      gemm_lds_kernel<true><<<grid, 256, 0, stream>>>(xb, wb, biasn, wwn, noise, sigma,
                                                      alpha, act, part);
    } else {
      gemm_lds_kernel<false><<<grid, 256, 0, stream>>>(xb, wb, biasn, wwn, noise, sigma,
                                                       alpha, act, nullptr);
    }
  } else {
    gemm_direct_kernel<<<grid, 256, 0, stream>>>(x, Bw, Bb, noise, sigma, alpha, act);
  }

  scan_kernel<<<(BBATCH * NN) / 256, 256, 0, stream>>>(noise, sigma, alpha, act);
  if (fuse) {
    reduce_kernel<<<MM * 2 / 256, 256, 0, stream>>>(part, Wb, alpha, out);
  }
  readout_kernel<<<MM, 256, 0, stream>>>(act, Ww, Wb, alpha, fuse ? 1 : 0, out);
}